// Round 6
// baseline (582.729 us; speedup 1.0000x reference)
//
#include <hip/hip_runtime.h>
#include <hip/hip_cooperative_groups.h>
#include <math.h>

namespace cg = cooperative_groups;

#define DIM 1024
#define WINDOW 16
#define EPS 0.01f

typedef __bf16 bf16_t;
typedef bf16_t bf16x8 __attribute__((ext_vector_type(8)));
typedef float f32x4 __attribute__((ext_vector_type(4)));

// ============================================================================
// R17: fused cooperative kernel (R16) + the two fixes:
//  (a) __threadfence() BEFORE AND AFTER every grid.sync(). Per-XCD L2s are
//      non-coherent; the harness poisons d_ws between iterations, so a reader
//      block's L2 holds stale (poison/zero) lines for qkv/yb unless it
//      invalidates after the barrier. Before-fence = release (writeback),
//      after-fence = acquire (invalidate). R16 had only the release half ->
//      zero/stale qkv -> zero output -> absmax 3.48 = max|ref|.
//  (b) hipLaunchCooperativeKernel rc checked; on failure fall back to the
//      four R14-verified dispatches (123.4us).
// All compute bodies are the R14-verified forms:
//  - 128x64 tile, BK=64, dbuf, global_load_lds staging, LDS swizzle
//    (row r, slot s holds chunk kc=(s-r)&7)
//  - split-K wave pairs (h0=wid&1 selects k-half), GEMM_REDUCE with
//    wave-uniform if(h0) branches and compile-time acc indices ONLY (rule #20)
//  - scalar-store epilogues (R15's LDS-transpose stores regressed)
// ============================================================================

#define GEMM_STAGE(buf, Ag, Bg, KK)                                            \
  {                                                                            \
    _Pragma("unroll")                                                          \
    for (int it = 0; it < 4; it++) {                                           \
      int c = it * 256 + t;                                                    \
      int r = c >> 3;                                                          \
      int kc = ((c & 7) - r) & 7;                                              \
      __builtin_amdgcn_global_load_lds(                                        \
          (const __attribute__((address_space(1))) void*)((Ag) + (size_t)r * (KK) + kc * 8), \
          (__attribute__((address_space(3))) void*)(As[buf] + c * 8), 16, 0, 0); \
    }                                                                          \
    _Pragma("unroll")                                                          \
    for (int it = 0; it < 2; it++) {                                           \
      int c = it * 256 + t;                                                    \
      int r = c >> 3;                                                          \
      int kc = ((c & 7) - r) & 7;                                              \
      __builtin_amdgcn_global_load_lds(                                        \
          (const __attribute__((address_space(1))) void*)((Bg) + (size_t)r * (KK) + kc * 8), \
          (__attribute__((address_space(3))) void*)(Bs[buf] + c * 8), 16, 0, 0); \
    }                                                                          \
  }

#define GEMM_DBUF_LOOP(Aptr, Bptr, KK)                                         \
  {                                                                            \
    const bf16_t* Abase = (Aptr) + (size_t)row0 * (KK);                        \
    const bf16_t* Bbase = (Bptr) + (size_t)col0 * (KK);                        \
    GEMM_STAGE(0, Abase, Bbase, KK)                                            \
    const int nIter = (KK) >> 6;                                               \
    for (int ki = 0; ki < nIter; ki++) {                                       \
      __syncthreads();                                                         \
      if (ki + 1 < nIter)                                                      \
        GEMM_STAGE((ki + 1) & 1, Abase + (ki + 1) * 64, Bbase + (ki + 1) * 64, KK) \
      const bf16_t* Ab = As[ki & 1];                                           \
      const bf16_t* Bb = Bs[ki & 1];                                           \
      bf16x8 af[4], bfr[4];                                                    \
      _Pragma("unroll")                                                        \
      for (int mi = 0; mi < 4; mi++) af[mi] = *(const bf16x8*)(Ab + aoff[mi]); \
      _Pragma("unroll")                                                        \
      for (int ni = 0; ni < 4; ni++) bfr[ni] = *(const bf16x8*)(Bb + boff[ni]); \
      _Pragma("unroll")                                                        \
      for (int mi = 0; mi < 4; mi++)                                           \
        _Pragma("unroll")                                                      \
        for (int ni = 0; ni < 4; ni++)                                         \
          acc[mi][ni] = __builtin_amdgcn_mfma_f32_16x16x32_bf16(af[mi], bfr[ni], \
                                                                acc[mi][ni], 0, 0, 0); \
    }                                                                          \
  }

#define GEMM_REDUCE()                                                          \
  {                                                                            \
    float* Xs = (float*)smem;                                                  \
    __syncthreads();                                                           \
    if (h0) {                                                                  \
      _Pragma("unroll")                                                        \
      for (int j = 0; j < 2; j++)                                              \
        _Pragma("unroll")                                                      \
        for (int ni = 0; ni < 4; ni++)                                         \
          *(f32x4*)(Xs + (size_t)(wid * 64 + ni * 16 + lcol) * 36 + j * 16 + lquad * 4) = \
              acc[j][ni];                                                      \
    } else {                                                                   \
      _Pragma("unroll")                                                        \
      for (int j = 0; j < 2; j++)                                              \
        _Pragma("unroll")                                                      \
        for (int ni = 0; ni < 4; ni++)                                         \
          *(f32x4*)(Xs + (size_t)(wid * 64 + ni * 16 + lcol) * 36 + j * 16 + lquad * 4) = \
              acc[2 + j][ni];                                                  \
    }                                                                          \
    __syncthreads();                                                           \
    if (h0) {                                                                  \
      _Pragma("unroll")                                                        \
      for (int j = 0; j < 2; j++)                                              \
        _Pragma("unroll")                                                      \
        for (int ni = 0; ni < 4; ni++) {                                       \
          f32x4 p = *(const f32x4*)(Xs + (size_t)((wid ^ 1) * 64 + ni * 16 + lcol) * 36 + \
                                    j * 16 + lquad * 4);                       \
          acc[j][ni] = acc[2 + j][ni] + p;                                     \
        }                                                                      \
    } else {                                                                   \
      _Pragma("unroll")                                                        \
      for (int j = 0; j < 2; j++)                                              \
        _Pragma("unroll")                                                      \
        for (int ni = 0; ni < 4; ni++) {                                       \
          f32x4 p = *(const f32x4*)(Xs + (size_t)((wid ^ 1) * 64 + ni * 16 + lcol) * 36 + \
                                    j * 16 + lquad * 4);                       \
          acc[j][ni] = acc[j][ni] + p;                                         \
        }                                                                      \
    }                                                                          \
  }

#define GEMM_PROLOGUE(TT, NBX, BYX)                                            \
  const int xcd = (TT) & 7;                                                    \
  const int jj = (TT) >> 3;                                                    \
  const int bx = jj % (NBX);                                                   \
  const int row0 = (xcd * (BYX) + jj / (NBX)) * 128;                           \
  const int col0 = bx * 64;                                                    \
  const int pr = (wid >> 1) * 64;                                              \
  const int h0 = wid & 1;                                                      \
  const int wm = wid * 32;                                                     \
  int aoff[4], boff[4];                                                        \
  _Pragma("unroll")                                                            \
  for (int mi = 0; mi < 4; mi++) {                                             \
    int r = pr + mi * 16 + lcol;                                               \
    aoff[mi] = r * 64 + (((h0 * 4 + lquad) + r) & 7) * 8;                      \
  }                                                                            \
  _Pragma("unroll")                                                            \
  for (int ni = 0; ni < 4; ni++) {                                             \
    int r = ni * 16 + lcol;                                                    \
    boff[ni] = r * 64 + (((h0 * 4 + lquad) + r) & 7) * 8;                      \
  }                                                                            \
  f32x4 acc[4][4] = {};

// ======================= fused cooperative kernel ===========================
__global__ __launch_bounds__(256, 2) void fused_all(
    const float* __restrict__ x, const float* __restrict__ wq,
    const float* __restrict__ wk, const float* __restrict__ wv,
    const float* __restrict__ wo, const float* __restrict__ qw,
    const float* __restrict__ kw, bf16_t* __restrict__ xb,
    bf16_t* __restrict__ wqkvb, bf16_t* __restrict__ wob,
    bf16_t* __restrict__ qkv, bf16_t* __restrict__ yb,
    float* __restrict__ out) {
  cg::grid_group grid = cg::this_grid();
  __shared__ __align__(16) char smem[49152];
  const int t = threadIdx.x;
  const int bid = blockIdx.x;
  const int lane = t & 63;
  const int wid = t >> 6;
  const int lquad = lane >> 4;
  const int lcol = lane & 15;

  // ================= phase 0: fp32 -> bf16 (8-elem chunks) ==================
  for (int c = bid * 256 + t; c < 851968; c += 131072) {
    const float* src;
    bf16_t* dst;
    int off;
    if (c < 524288) { src = x; dst = xb; off = c; }
    else if (c < 655360) { src = wq; dst = wqkvb; off = c - 524288; }
    else if (c < 688128) { src = wk; dst = wqkvb + (size_t)1024 * DIM; off = c - 655360; }
    else if (c < 720896) { src = wv; dst = wqkvb + (size_t)1280 * DIM; off = c - 688128; }
    else { src = wo; dst = wob; off = c - 720896; }
    float4 f0 = ((const float4*)src)[off * 2];
    float4 f1 = ((const float4*)src)[off * 2 + 1];
    bf16x8 o8 = {(bf16_t)f0.x, (bf16_t)f0.y, (bf16_t)f0.z, (bf16_t)f0.w,
                 (bf16_t)f1.x, (bf16_t)f1.y, (bf16_t)f1.z, (bf16_t)f1.w};
    ((bf16x8*)dst)[off] = o8;
  }
  __threadfence();   // release: writeback this XCD's L2
  grid.sync();
  __threadfence();   // acquire: invalidate stale lines before reading

  // ================= phase 1: QKV GEMM + fused RMSNorm ======================
  {
    bf16_t (*As)[128 * 64] = (bf16_t(*)[128 * 64])smem;
    bf16_t (*Bs)[64 * 64] = (bf16_t(*)[64 * 64])(smem + 32768);
    for (int tt = bid; tt < 768; tt += 512) {
      GEMM_PROLOGUE(tt, 24, 4)
      GEMM_DBUF_LOOP(xb, wqkvb, 1024)
      GEMM_REDUCE()

      const int hcol = bx;                 // 0..23; >=20 is V (no norm)
      const bool isv = (hcol >= 20);
      float wreg[4];
      if (!isv) {
        const float* wp = (hcol < 16) ? qw : kw;
#pragma unroll
        for (int ni = 0; ni < 4; ni++) wreg[ni] = wp[ni * 16 + lcol];
      }
#pragma unroll
      for (int mi = 0; mi < 2; mi++) {
#pragma unroll
        for (int r = 0; r < 4; r++) {
          float norm = 1.0f;
          if (!isv) {
            float ss = 0.0f;
#pragma unroll
            for (int ni = 0; ni < 4; ni++) ss += acc[mi][ni][r] * acc[mi][ni][r];
#pragma unroll
            for (int off = 8; off >= 1; off >>= 1) ss += __shfl_xor(ss, off);
            norm = rsqrtf(ss * (1.0f / 64.0f) + EPS);
          }
          size_t base = (size_t)(row0 + wm + mi * 16 + lquad * 4 + r) * 1536 + col0 + lcol;
#pragma unroll
          for (int ni = 0; ni < 4; ni++) {
            float v = acc[mi][ni][r] * norm;
            if (!isv) v *= wreg[ni];
            qkv[base + ni * 16] = (bf16_t)v;
          }
        }
      }
      __syncthreads();  // Xs reads done before next tile restages As[0]
    }
  }
  __threadfence();
  grid.sync();
  __threadfence();

  // ================= phase 2: banded ALiBi attention ========================
  // block = (qtile, half); wave w owns kvh=w, heads {half*8+w, half*8+w+4}
  {
    const int w4 = wid;
    const int qt = bid >> 1;
    const int half = bid & 1;
    const int bb = qt >> 7;
    const int i0loc = (qt & 127) << 4;
    const int rowbase = bb << 11;
    const int rowg0 = rowbase + i0loc;

    bf16_t* Ks = (bf16_t*)smem;                 // [4][32][72]  18KB
    bf16_t* VTs = (bf16_t*)(smem + 18432);      // [4][64][40]  20KB
    bf16_t* Ps = (bf16_t*)(smem + 38912);       // [4][16][40]   5KB

#pragma unroll
    for (int it = 0; it < 4; it++) {
      int cidx = it * 256 + t;
      int kvh = cidx >> 8;
      int key = (cidx >> 3) & 31;
      int dc = cidx & 7;
      int jloc = i0loc - 16 + key;
      int rg = rowbase + (jloc < 0 ? 0 : jloc);
      const bf16_t* src = qkv + (size_t)rg * 1536 + 1024 + kvh * 64 + dc * 8;
      bf16x8 kval = *(const bf16x8*)src;
      *(bf16x8*)(Ks + (kvh * 32 + key) * 72 + dc * 8) = kval;
      bf16x8 vval = *(const bf16x8*)(src + 256);  // V is 256 elems after K
      int kslot = ((key >> 3) ^ (dc & 3)) * 8 + (key & 7);
#pragma unroll
      for (int e = 0; e < 8; e++) VTs[(kvh * 64 + dc * 8 + e) * 40 + kslot] = vval[e];
    }

    const int col = lcol;
    const int quad = lquad;
    const int kvh = w4;

    // hoist BOTH heads' Q loads before the barrier (overlap staging drain)
    const bf16_t* qrow0 = qkv + (size_t)(rowg0 + col) * 1536 + (half * 8 + w4) * 64;
    bf16x8 qfa0 = *(const bf16x8*)(qrow0 + quad * 8);
    bf16x8 qfa1 = *(const bf16x8*)(qrow0 + 32 + quad * 8);
    bf16x8 qfb0 = *(const bf16x8*)(qrow0 + 256 + quad * 8);      // head +4
    bf16x8 qfb1 = *(const bf16x8*)(qrow0 + 256 + 32 + quad * 8);

    __syncthreads();

    bf16x8 kf[2][2];
#pragma unroll
    for (int kt = 0; kt < 2; kt++)
#pragma unroll
      for (int kc2 = 0; kc2 < 2; kc2++)
        kf[kt][kc2] = *(const bf16x8*)(Ks + (kvh * 32 + kt * 16 + col) * 72 + kc2 * 32 + quad * 8);
    bf16x8 vf[4];
#pragma unroll
    for (int nt = 0; nt < 4; nt++) {
      int dim = nt * 16 + col;
      int kchunk = quad ^ ((dim >> 3) & 3);
      vf[nt] = *(const bf16x8*)(VTs + (kvh * 64 + dim) * 40 + kchunk * 8);
    }

    const bool t0dead = (i0loc == 0);

#pragma unroll
    for (int hp = 0; hp < 2; hp++) {
      const int h = half * 8 + w4 + hp * 4;
      const float slope = exp2f(-0.5f * (float)(h + 1));
      bf16x8 qf0 = hp ? qfb0 : qfa0;  // hp compile-time (unrolled)
      bf16x8 qf1 = hp ? qfb1 : qfa1;

      f32x4 s0 = {}, s1 = {};
      s0 = __builtin_amdgcn_mfma_f32_16x16x32_bf16(qf0, kf[0][0], s0, 0, 0, 0);
      s0 = __builtin_amdgcn_mfma_f32_16x16x32_bf16(qf1, kf[0][1], s0, 0, 0, 0);
      s1 = __builtin_amdgcn_mfma_f32_16x16x32_bf16(qf0, kf[1][0], s1, 0, 0, 0);
      s1 = __builtin_amdgcn_mfma_f32_16x16x32_bf16(qf1, kf[1][1], s1, 0, 0, 0);

      float sc0[4], sc1[4];
#pragma unroll
      for (int r = 0; r < 4; r++) {
        int rel0 = col - 16 - (quad * 4 + r);
        int rel1 = rel0 + 16;
        bool m0 = t0dead || (rel0 < -WINDOW);
        bool m1 = (rel1 > 0);
        sc0[r] = m0 ? -INFINITY : s0[r] * 0.125f + slope * (float)rel0;
        sc1[r] = m1 ? -INFINITY : s1[r] * 0.125f + slope * (float)rel1;
      }
      float mx[4], sum[4], p0[4], p1[4];
#pragma unroll
      for (int r = 0; r < 4; r++) mx[r] = fmaxf(sc0[r], sc1[r]);
#pragma unroll
      for (int off = 8; off >= 1; off >>= 1)
#pragma unroll
        for (int r = 0; r < 4; r++) mx[r] = fmaxf(mx[r], __shfl_xor(mx[r], off));
#pragma unroll
      for (int r = 0; r < 4; r++) {
        p0[r] = __expf(sc0[r] - mx[r]);
        p1[r] = __expf(sc1[r] - mx[r]);
        sum[r] = p0[r] + p1[r];
      }
#pragma unroll
      for (int off = 8; off >= 1; off >>= 1)
#pragma unroll
        for (int r = 0; r < 4; r++) sum[r] += __shfl_xor(sum[r], off);

#pragma unroll
      for (int r = 0; r < 4; r++) {
        Ps[(w4 * 16 + quad * 4 + r) * 40 + col] = (bf16_t)p0[r];
        Ps[(w4 * 16 + quad * 4 + r) * 40 + 16 + col] = (bf16_t)p1[r];
      }
      // no __syncthreads: Ps slab is wave-private; DS ops in-order within wave
      bf16x8 pf = *(const bf16x8*)(Ps + (w4 * 16 + col) * 40 + quad * 8);

      f32x4 o[4] = {};
#pragma unroll
      for (int nt = 0; nt < 4; nt++)
        o[nt] = __builtin_amdgcn_mfma_f32_16x16x32_bf16(pf, vf[nt], o[nt], 0, 0, 0);

      float rs[4];
#pragma unroll
      for (int r = 0; r < 4; r++) rs[r] = __builtin_amdgcn_rcpf(sum[r]);
#pragma unroll
      for (int nt = 0; nt < 4; nt++)
#pragma unroll
        for (int r = 0; r < 4; r++)
          yb[(size_t)(rowg0 + quad * 4 + r) * 1024 + h * 64 + nt * 16 + col] =
              (bf16_t)(o[nt][r] * rs[r]);
    }
  }
  __threadfence();
  grid.sync();
  __threadfence();

  // ================= phase 3: out projection (512 tiles, 1:1) ===============
  {
    bf16_t (*As)[128 * 64] = (bf16_t(*)[128 * 64])smem;
    bf16_t (*Bs)[64 * 64] = (bf16_t(*)[64 * 64])(smem + 32768);
    GEMM_PROLOGUE(bid, 16, 4)
    GEMM_DBUF_LOOP(yb, wob, 1024)
    GEMM_REDUCE()
#pragma unroll
    for (int mi = 0; mi < 2; mi++)
#pragma unroll
      for (int ni = 0; ni < 4; ni++) {
        size_t base = (size_t)(row0 + wm + mi * 16 + lquad * 4) * 1024 + col0 + ni * 16 + lcol;
#pragma unroll
        for (int r = 0; r < 4; r++)
          out[base + (size_t)r * 1024] = acc[mi][ni][r];
      }
  }
}

// ======================= fallback: R14's four kernels =======================
__global__ __launch_bounds__(256) void f2bf_all(const float* __restrict__ x,
                                                const float* __restrict__ wq,
                                                const float* __restrict__ wk,
                                                const float* __restrict__ wv,
                                                const float* __restrict__ wo,
                                                bf16_t* __restrict__ xb,
                                                bf16_t* __restrict__ wqkvb,
                                                bf16_t* __restrict__ wob) {
  int i = blockIdx.x * blockDim.x + threadIdx.x;
  const float* src;
  bf16_t* dst;
  int off;
  if (i < 524288) { src = x; dst = xb; off = i; }
  else if (i < 655360) { src = wq; dst = wqkvb; off = i - 524288; }
  else if (i < 688128) { src = wk; dst = wqkvb + (size_t)1024 * DIM; off = i - 655360; }
  else if (i < 720896) { src = wv; dst = wqkvb + (size_t)1280 * DIM; off = i - 688128; }
  else { src = wo; dst = wob; off = i - 720896; }
  float4 f0 = ((const float4*)src)[off * 2];
  float4 f1 = ((const float4*)src)[off * 2 + 1];
  bf16x8 o8 = {(bf16_t)f0.x, (bf16_t)f0.y, (bf16_t)f0.z, (bf16_t)f0.w,
               (bf16_t)f1.x, (bf16_t)f1.y, (bf16_t)f1.z, (bf16_t)f1.w};
  ((bf16x8*)dst)[off] = o8;
}

__global__ __launch_bounds__(256, 3) void gemm_qkv_rms(const bf16_t* __restrict__ A,
                                                       const bf16_t* __restrict__ B,
                                                       bf16_t* __restrict__ C,
                                                       const float* __restrict__ qw,
                                                       const float* __restrict__ kw,
                                                       int M, int N, int K) {
  __shared__ __align__(16) char smem[49152];
  bf16_t (*As)[128 * 64] = (bf16_t(*)[128 * 64])smem;
  bf16_t (*Bs)[64 * 64] = (bf16_t(*)[64 * 64])(smem + 32768);
  const int t = threadIdx.x;
  const int lane = t & 63;
  const int wid = t >> 6;
  const int lquad = lane >> 4;
  const int lcol = lane & 15;
  GEMM_PROLOGUE((int)blockIdx.x, 24, 4)
  GEMM_DBUF_LOOP(A, B, K)
  GEMM_REDUCE()

  const int hcol = bx;
  const bool isv = (hcol >= 20);
  float wreg[4];
  if (!isv) {
    const float* wp = (hcol < 16) ? qw : kw;
#pragma unroll
    for (int ni = 0; ni < 4; ni++) wreg[ni] = wp[ni * 16 + lcol];
  }
#pragma unroll
  for (int mi = 0; mi < 2; mi++) {
#pragma unroll
    for (int r = 0; r < 4; r++) {
      float norm = 1.0f;
      if (!isv) {
        float ss = 0.0f;
#pragma unroll
        for (int ni = 0; ni < 4; ni++) ss += acc[mi][ni][r] * acc[mi][ni][r];
#pragma unroll
        for (int off = 8; off >= 1; off >>= 1) ss += __shfl_xor(ss, off);
        norm = rsqrtf(ss * (1.0f / 64.0f) + EPS);
      }
      size_t base = (size_t)(row0 + wm + mi * 16 + lquad * 4 + r) * N + col0 + lcol;
#pragma unroll
      for (int ni = 0; ni < 4; ni++) {
        float v = acc[mi][ni][r] * norm;
        if (!isv) v *= wreg[ni];
        C[base + ni * 16] = (bf16_t)v;
      }
    }
  }
}

template <int NBX, int BYX>
__global__ __launch_bounds__(256, 3) void gemm_bf16(const bf16_t* __restrict__ A,
                                                    const bf16_t* __restrict__ B,
                                                    float* __restrict__ C,
                                                    int M, int N, int K) {
  __shared__ __align__(16) char smem[49152];
  bf16_t (*As)[128 * 64] = (bf16_t(*)[128 * 64])smem;
  bf16_t (*Bs)[64 * 64] = (bf16_t(*)[64 * 64])(smem + 32768);
  const int t = threadIdx.x;
  const int lane = t & 63;
  const int wid = t >> 6;
  const int lquad = lane >> 4;
  const int lcol = lane & 15;
  GEMM_PROLOGUE((int)blockIdx.x, NBX, BYX)
  GEMM_DBUF_LOOP(A, B, K)
  GEMM_REDUCE()
#pragma unroll
  for (int mi = 0; mi < 2; mi++)
#pragma unroll
    for (int ni = 0; ni < 4; ni++) {
      size_t base = (size_t)(row0 + wm + mi * 16 + lquad * 4) * N + col0 + ni * 16 + lcol;
#pragma unroll
      for (int r = 0; r < 4; r++)
        C[base + (size_t)r * N] = acc[mi][ni][r];
    }
}

#define LKP 72
#define LVP 40

__global__ __launch_bounds__(1024) void attn_mfma(const bf16_t* __restrict__ qkv,
                                                  bf16_t* __restrict__ y) {
  __shared__ bf16_t Ks[4][32][LKP];
  __shared__ bf16_t VTs[4][64][LVP];
  __shared__ bf16_t Ps[16][16][LVP];

  const int t = threadIdx.x;
  const int lane = t & 63;
  const int w = t >> 6;
  const int b = blockIdx.x >> 7;
  const int i0loc = (blockIdx.x & 127) << 4;
  const int rowbase = b << 11;
  const int rowg0 = rowbase + i0loc;

  {
    int kvh = t >> 8;
    int key = (t >> 3) & 31;
    int dc = t & 7;
    int jloc = i0loc - 16 + key;
    int rg = rowbase + (jloc < 0 ? 0 : jloc);
    const bf16_t* src = qkv + (size_t)rg * 1536 + 1024 + kvh * 64 + dc * 8;
    bf16x8 kval = *(const bf16x8*)src;
    *(bf16x8*)(&Ks[kvh][key][dc * 8]) = kval;
    bf16x8 vval = *(const bf16x8*)(src + 256);
    int kslot = ((key >> 3) ^ (dc & 3)) * 8 + (key & 7);
#pragma unroll
    for (int e = 0; e < 8; e++) VTs[kvh][dc * 8 + e][kslot] = vval[e];
  }

  const int col = lane & 15;
  const int quad = lane >> 4;
  const int h = w;
  const int kvh = w & 3;
  const float slope = exp2f(-0.5f * (float)(h + 1));

  const bf16_t* qrow = qkv + (size_t)(rowg0 + col) * 1536 + h * 64;
  bf16x8 qf0 = *(const bf16x8*)(qrow + quad * 8);
  bf16x8 qf1 = *(const bf16x8*)(qrow + 32 + quad * 8);

  __syncthreads();

  bf16x8 kf[2][2];
#pragma unroll
  for (int kt = 0; kt < 2; kt++)
#pragma unroll
    for (int kc = 0; kc < 2; kc++)
      kf[kt][kc] = *(const bf16x8*)(&Ks[kvh][kt * 16 + col][kc * 32 + quad * 8]);
  bf16x8 vf[4];
#pragma unroll
  for (int nt = 0; nt < 4; nt++) {
    int dim = nt * 16 + col;
    int kchunk = quad ^ ((dim >> 3) & 3);
    vf[nt] = *(const bf16x8*)(&VTs[kvh][dim][kchunk * 8]);
  }

  f32x4 s0 = {}, s1 = {};
  s0 = __builtin_amdgcn_mfma_f32_16x16x32_bf16(qf0, kf[0][0], s0, 0, 0, 0);
  s0 = __builtin_amdgcn_mfma_f32_16x16x32_bf16(qf1, kf[0][1], s0, 0, 0, 0);
  s1 = __builtin_amdgcn_mfma_f32_16x16x32_bf16(qf0, kf[1][0], s1, 0, 0, 0);
  s1 = __builtin_amdgcn_mfma_f32_16x16x32_bf16(qf1, kf[1][1], s1, 0, 0, 0);

  const bool t0dead = (i0loc == 0);
  float sc0[4], sc1[4];
#pragma unroll
  for (int r = 0; r < 4; r++) {
    int rel0 = col - 16 - (quad * 4 + r);
    int rel1 = rel0 + 16;
    bool m0 = t0dead || (rel0 < -WINDOW);
    bool m1 = (rel1 > 0);
    sc0[r] = m0 ? -INFINITY : s0[r] * 0.125f + slope * (float)rel0;
    sc1[r] = m1 ? -INFINITY : s1[r] * 0.125f + slope * (float)rel1;
  }
  float mx[4], sum[4], p0[4], p1[4];
#pragma unroll
  for (int r = 0; r < 4; r++) mx[r] = fmaxf(sc0[r], sc1[r]);
#pragma unroll
  for (int off = 8; off >= 1; off >>= 1)
#pragma unroll
    for (int r = 0; r < 4; r++) mx[r] = fmaxf(mx[r], __shfl_xor(mx[r], off));
#pragma unroll
  for (int r = 0; r < 4; r++) {
    p0[r] = __expf(sc0[r] - mx[r]);
    p1[r] = __expf(sc1[r] - mx[r]);
    sum[r] = p0[r] + p1[r];
  }
#pragma unroll
  for (int off = 8; off >= 1; off >>= 1)
#pragma unroll
    for (int r = 0; r < 4; r++) sum[r] += __shfl_xor(sum[r], off);

#pragma unroll
  for (int r = 0; r < 4; r++) {
    Ps[w][quad * 4 + r][col] = (bf16_t)p0[r];
    Ps[w][quad * 4 + r][16 + col] = (bf16_t)p1[r];
  }
  bf16x8 pf = *(const bf16x8*)(&Ps[w][col][quad * 8]);

  f32x4 o[4] = {};
#pragma unroll
  for (int nt = 0; nt < 4; nt++)
    o[nt] = __builtin_amdgcn_mfma_f32_16x16x32_bf16(pf, vf[nt], o[nt], 0, 0, 0);

#pragma unroll
  for (int nt = 0; nt < 4; nt++)
#pragma unroll
    for (int r = 0; r < 4; r++)
      y[(size_t)(rowg0 + quad * 4 + r) * 1024 + h * 64 + nt * 16 + col] =
          (bf16_t)(o[nt][r] / sum[r]);
}

extern "C" void kernel_launch(void* const* d_in, const int* in_sizes, int n_in,
                              void* d_out, int out_size, void* d_ws, size_t ws_size,
                              hipStream_t stream) {
  const float* x  = (const float*)d_in[0];
  const float* wq = (const float*)d_in[1];
  const float* wk = (const float*)d_in[2];
  const float* wv = (const float*)d_in[3];
  const float* wo = (const float*)d_in[4];
  const float* qw = (const float*)d_in[5];
  const float* kw = (const float*)d_in[6];
  float* out = (float*)d_out;

  const int M = 4096;  // B*L

  bf16_t* xb    = (bf16_t*)d_ws;
  bf16_t* wqkvb = xb + (size_t)M * DIM;        // [1536, 1024]
  bf16_t* wob   = wqkvb + (size_t)1536 * DIM;  // [1024, 1024]
  bf16_t* qkv   = wob + (size_t)DIM * DIM;     // [4096, 1536]
  bf16_t* yb    = qkv + (size_t)M * 1536;      // [4096, 1024]

  void* args[] = {(void*)&x, (void*)&wq, (void*)&wk, (void*)&wv, (void*)&wo,
                  (void*)&qw, (void*)&kw, (void*)&xb, (void*)&wqkvb, (void*)&wob,
                  (void*)&qkv, (void*)&yb, (void*)&out};
  hipError_t rc = hipLaunchCooperativeKernel((void*)fused_all, dim3(512), dim3(256),
                                             args, 0, stream);
  if (rc != hipSuccess) {
    // fallback: R14's verified 4-dispatch pipeline (123.4 us)
    dim3 blk(256);
    f2bf_all<<<3328, blk, 0, stream>>>(x, wq, wk, wv, wo, xb, wqkvb, wob);
    gemm_qkv_rms<<<768, blk, 0, stream>>>(xb, wqkvb, qkv, qw, kw, M, 1536, DIM);
    attn_mfma<<<256, dim3(1024), 0, stream>>>(qkv, yb);
    gemm_bf16<16, 4><<<512, blk, 0, stream>>>(yb, wob, out, M, DIM, DIM);
  }
}

// Round 7
// 124.785 us; speedup vs baseline: 4.6699x; 4.6699x over previous
//
#include <hip/hip_runtime.h>
#include <math.h>

#define DIM 1024
#define NH 16
#define NKV 4
#define HD 64
#define WINDOW 16
#define EPS 0.01f

typedef __bf16 bf16_t;
typedef bf16_t bf16x8 __attribute__((ext_vector_type(8)));
typedef bf16_t bf16x4 __attribute__((ext_vector_type(4)));
typedef float f32x4 __attribute__((ext_vector_type(4)));

// ============================================================================
// R18 = R14's verified 4-dispatch pipeline (123.4us) with ONE change:
// attention restructured from 256 blocks x 1024 thr (1 block/CU, latency-
// bound, nothing to hide stalls) to 512 blocks x 256 thr (R17-phase-2's
// verified dual-head remap): block=(qtile, half), wave w owns kvh=w and runs
// heads {half*8+w, half*8+w+4} off the same K/V fragments. ~43KB LDS ->
// 2+ blocks/CU so a co-resident block's compute hides staging latency.
// Learned (R17): total dur carries ~88us of fixed harness overhead (poison
// fills in the timed window); kernel work totals only ~36us. grid.sync
// cooperative fusion costs ~150us/barrier -> permanently rejected.
// ============================================================================

// ---------------- fused fp32 -> bf16 conversion of all 5 tensors ----------------
__global__ __launch_bounds__(256) void f2bf_all(const float* __restrict__ x,
                                                const float* __restrict__ wq,
                                                const float* __restrict__ wk,
                                                const float* __restrict__ wv,
                                                const float* __restrict__ wo,
                                                bf16_t* __restrict__ xb,
                                                bf16_t* __restrict__ wqkvb,
                                                bf16_t* __restrict__ wob) {
  int i = blockIdx.x * blockDim.x + threadIdx.x;
  const float* src;
  bf16_t* dst;
  int off;
  if (i < 1048576) { src = x; dst = xb; off = i; }
  else if (i < 1310720) { src = wq; dst = wqkvb; off = i - 1048576; }
  else if (i < 1376256) { src = wk; dst = wqkvb + (size_t)1024 * DIM; off = i - 1310720; }
  else if (i < 1441792) { src = wv; dst = wqkvb + (size_t)1280 * DIM; off = i - 1376256; }
  else { src = wo; dst = wob; off = i - 1441792; }
  float4 f = ((const float4*)src)[off];
  bf16x4 o = {(bf16_t)f.x, (bf16_t)f.y, (bf16_t)f.z, (bf16_t)f.w};
  ((bf16x4*)dst)[off] = o;
}

// ========== 128(M)x64(N), BK=64, double-buffered swizzled-staging GEMM ========
// split-K wave pairs: waves {0,1} rows 0-63, {2,3} rows 64-127; each wave
// computes a full 64x64 partial over its 32-wide k-half (h0=wid&1).
// 16 MFMA : 8 ds_read_b128 per k-step = 512B LDS/MFMA.
// GEMM_REDUCE: wave-uniform if(h0), compile-time acc indices ONLY (rule #20).
// LDS swizzle: row r, slot s holds global chunk kc=(s-r)&7; reader slot=(kc+r)&7.

#define GEMM_STAGE(buf, Ag, Bg)                                                 \
  {                                                                             \
    _Pragma("unroll")                                                           \
    for (int it = 0; it < 4; it++) {                                            \
      int c = it * 256 + t;                                                     \
      int r = c >> 3;                                                           \
      int kc = ((c & 7) - r) & 7;                                               \
      __builtin_amdgcn_global_load_lds(                                         \
          (const __attribute__((address_space(1))) void*)((Ag) + (size_t)r * K + kc * 8), \
          (__attribute__((address_space(3))) void*)(As[buf] + c * 8), 16, 0, 0); \
    }                                                                           \
    _Pragma("unroll")                                                           \
    for (int it = 0; it < 2; it++) {                                            \
      int c = it * 256 + t;                                                     \
      int r = c >> 3;                                                           \
      int kc = ((c & 7) - r) & 7;                                               \
      __builtin_amdgcn_global_load_lds(                                         \
          (const __attribute__((address_space(1))) void*)((Bg) + (size_t)r * K + kc * 8), \
          (__attribute__((address_space(3))) void*)(Bs[buf] + c * 8), 16, 0, 0); \
    }                                                                           \
  }

#define GEMM_DBUF_LOOP(Aptr, Bptr)                                              \
  {                                                                             \
    const bf16_t* Abase = Aptr + (size_t)row0 * K;                              \
    const bf16_t* Bbase = Bptr + (size_t)col0 * K;                              \
    GEMM_STAGE(0, Abase, Bbase)                                                 \
    const int nIter = K >> 6;                                                   \
    for (int ki = 0; ki < nIter; ki++) {                                        \
      __syncthreads();                                                          \
      if (ki + 1 < nIter)                                                       \
        GEMM_STAGE((ki + 1) & 1, Abase + (ki + 1) * 64, Bbase + (ki + 1) * 64)  \
      const bf16_t* Ab = As[ki & 1];                                            \
      const bf16_t* Bb = Bs[ki & 1];                                            \
      bf16x8 af[4], bfr[4];                                                     \
      _Pragma("unroll")                                                         \
      for (int mi = 0; mi < 4; mi++) af[mi] = *(const bf16x8*)(Ab + aoff[mi]);  \
      _Pragma("unroll")                                                         \
      for (int ni = 0; ni < 4; ni++) bfr[ni] = *(const bf16x8*)(Bb + boff[ni]); \
      _Pragma("unroll")                                                         \
      for (int mi = 0; mi < 4; mi++)                                            \
        _Pragma("unroll")                                                       \
        for (int ni = 0; ni < 4; ni++)                                          \
          acc[mi][ni] = __builtin_amdgcn_mfma_f32_16x16x32_bf16(af[mi], bfr[ni], \
                                                                acc[mi][ni], 0, 0, 0); \
    }                                                                           \
  }

#define GEMM_REDUCE()                                                           \
  {                                                                             \
    float* Xs = (float*)smem;                                                   \
    __syncthreads();                                                            \
    if (h0) {                                                                   \
      _Pragma("unroll")                                                         \
      for (int j = 0; j < 2; j++)                                               \
        _Pragma("unroll")                                                       \
        for (int ni = 0; ni < 4; ni++)                                          \
          *(f32x4*)(Xs + (size_t)(wid * 64 + ni * 16 + lcol) * 36 + j * 16 + lquad * 4) = \
              acc[j][ni];                                                       \
    } else {                                                                    \
      _Pragma("unroll")                                                         \
      for (int j = 0; j < 2; j++)                                               \
        _Pragma("unroll")                                                       \
        for (int ni = 0; ni < 4; ni++)                                          \
          *(f32x4*)(Xs + (size_t)(wid * 64 + ni * 16 + lcol) * 36 + j * 16 + lquad * 4) = \
              acc[2 + j][ni];                                                   \
    }                                                                           \
    __syncthreads();                                                            \
    if (h0) {                                                                   \
      _Pragma("unroll")                                                         \
      for (int j = 0; j < 2; j++)                                               \
        _Pragma("unroll")                                                       \
        for (int ni = 0; ni < 4; ni++) {                                        \
          f32x4 p = *(const f32x4*)(Xs + (size_t)((wid ^ 1) * 64 + ni * 16 + lcol) * 36 + \
                                    j * 16 + lquad * 4);                        \
          acc[j][ni] = acc[2 + j][ni] + p;                                      \
        }                                                                       \
    } else {                                                                    \
      _Pragma("unroll")                                                         \
      for (int j = 0; j < 2; j++)                                               \
        _Pragma("unroll")                                                       \
        for (int ni = 0; ni < 4; ni++) {                                        \
          f32x4 p = *(const f32x4*)(Xs + (size_t)((wid ^ 1) * 64 + ni * 16 + lcol) * 36 + \
                                    j * 16 + lquad * 4);                        \
          acc[j][ni] = acc[j][ni] + p;                                          \
        }                                                                       \
    }                                                                           \
  }

#define GEMM_PROLOGUE(NBX, BYX)                                                 \
  const int t = threadIdx.x;                                                    \
  const int lane = t & 63;                                                      \
  const int wid = t >> 6;                                                       \
  const int xcd = blockIdx.x & 7;                                               \
  const int jj = blockIdx.x >> 3;                                               \
  const int bx = jj % (NBX);                                                    \
  const int row0 = (xcd * (BYX) + jj / (NBX)) * 128;                            \
  const int col0 = bx * 64;                                                     \
  const int pr = (wid >> 1) * 64;                                               \
  const int h0 = wid & 1;                                                       \
  const int wm = wid * 32;                                                      \
  const int lquad = lane >> 4;                                                  \
  const int lcol = lane & 15;                                                   \
  int aoff[4], boff[4];                                                         \
  _Pragma("unroll")                                                             \
  for (int mi = 0; mi < 4; mi++) {                                              \
    int r = pr + mi * 16 + lcol;                                                \
    aoff[mi] = r * 64 + (((h0 * 4 + lquad) + r) & 7) * 8;                       \
  }                                                                             \
  _Pragma("unroll")                                                             \
  for (int ni = 0; ni < 4; ni++) {                                              \
    int r = ni * 16 + lcol;                                                     \
    boff[ni] = r * 64 + (((h0 * 4 + lquad) + r) & 7) * 8;                       \
  }                                                                             \
  f32x4 acc[4][4] = {};

// ---------------- QKV GEMM with fused per-head RMSNorm epilogue ----------------
__global__ __launch_bounds__(256, 3) void gemm_qkv_rms(const bf16_t* __restrict__ A,
                                                       const bf16_t* __restrict__ B,
                                                       bf16_t* __restrict__ C,
                                                       const float* __restrict__ qw,
                                                       const float* __restrict__ kw,
                                                       int M, int N, int K) {
  __shared__ __align__(16) char smem[49152];
  bf16_t (*As)[128 * 64] = (bf16_t(*)[128 * 64])smem;
  bf16_t (*Bs)[64 * 64] = (bf16_t(*)[64 * 64])(smem + 32768);
  GEMM_PROLOGUE(24, 4)
  GEMM_DBUF_LOOP(A, B)
  GEMM_REDUCE()

  const int hcol = bx;                   // 0..23
  const bool isv = (hcol >= 20);
  float wreg[4];
  if (!isv) {
    const float* wp = (hcol < 16) ? qw : kw;
#pragma unroll
    for (int ni = 0; ni < 4; ni++) wreg[ni] = wp[ni * 16 + lcol];
  }

#pragma unroll
  for (int mi = 0; mi < 2; mi++) {
#pragma unroll
    for (int r = 0; r < 4; r++) {
      float norm = 1.0f;
      if (!isv) {
        float ss = 0.0f;
#pragma unroll
        for (int ni = 0; ni < 4; ni++) ss += acc[mi][ni][r] * acc[mi][ni][r];
#pragma unroll
        for (int off = 8; off >= 1; off >>= 1) ss += __shfl_xor(ss, off);
        norm = rsqrtf(ss * (1.0f / 64.0f) + EPS);
      }
      size_t base = (size_t)(row0 + wm + mi * 16 + lquad * 4 + r) * N + col0 + lcol;
#pragma unroll
      for (int ni = 0; ni < 4; ni++) {
        float v = acc[mi][ni][r] * norm;
        if (!isv) v *= wreg[ni];
        C[base + ni * 16] = (bf16_t)v;
      }
    }
  }
}

// ---------------- bf16 MFMA GEMM (128x64, split-K waves, XCD-swizzled) --------
template <typename CT, int NBX, int BYX>
__global__ __launch_bounds__(256, 3) void gemm_bf16(const bf16_t* __restrict__ A,
                                                    const bf16_t* __restrict__ B,
                                                    CT* __restrict__ C,
                                                    int M, int N, int K) {
  __shared__ __align__(16) char smem[49152];
  bf16_t (*As)[128 * 64] = (bf16_t(*)[128 * 64])smem;
  bf16_t (*Bs)[64 * 64] = (bf16_t(*)[64 * 64])(smem + 32768);
  GEMM_PROLOGUE(NBX, BYX)
  GEMM_DBUF_LOOP(A, B)
  GEMM_REDUCE()

#pragma unroll
  for (int mi = 0; mi < 2; mi++)
#pragma unroll
    for (int ni = 0; ni < 4; ni++) {
      size_t base = (size_t)(row0 + wm + mi * 16 + lquad * 4) * N + col0 + ni * 16 + lcol;
#pragma unroll
      for (int r = 0; r < 4; r++)
        C[base + (size_t)r * N] = (CT)acc[mi][ni][r];
    }
}

// ---------- MFMA banded ALiBi attention (dual-head waves, 2 blocks/CU) -------
// block = (qtile, half); wave w in [0,4) owns kvh=w, heads {half*8+w, half*8+w+4}.
// Verified correct as R17's phase 2 (passed, absmax 0.0156).
#define LKP 72  // K row stride
#define LVP 40  // VT / P row stride

__global__ __launch_bounds__(256) void attn_mfma(const bf16_t* __restrict__ qkv,
                                                 bf16_t* __restrict__ y) {
  __shared__ bf16_t Ks[4][32][LKP];    // 18 KB
  __shared__ bf16_t VTs[4][64][LVP];   // 20 KB
  __shared__ bf16_t Ps[4][16][LVP];    //  5 KB  (per-wave slab)

  const int t = threadIdx.x;
  const int lane = t & 63;
  const int w4 = t >> 6;               // 0..3
  const int qt = blockIdx.x >> 1;
  const int half = blockIdx.x & 1;
  const int b = qt >> 7;
  const int i0loc = (qt & 127) << 4;
  const int rowbase = b << 11;
  const int rowg0 = rowbase + i0loc;

  // stage K and V: 1024 chunks over 256 threads (4 iters)
#pragma unroll
  for (int it = 0; it < 4; it++) {
    int cidx = it * 256 + t;
    int kvh = cidx >> 8;
    int key = (cidx >> 3) & 31;
    int dc = cidx & 7;
    int jloc = i0loc - 16 + key;
    int rg = rowbase + (jloc < 0 ? 0 : jloc);
    const bf16_t* src = qkv + (size_t)rg * 1536 + 1024 + kvh * 64 + dc * 8;
    bf16x8 kval = *(const bf16x8*)src;
    *(bf16x8*)(&Ks[kvh][key][dc * 8]) = kval;
    bf16x8 vval = *(const bf16x8*)(src + 256);   // V is 256 elems after K
    int kslot = ((key >> 3) ^ (dc & 3)) * 8 + (key & 7);
#pragma unroll
    for (int e = 0; e < 8; e++) VTs[kvh][dc * 8 + e][kslot] = vval[e];
  }

  const int col = lane & 15;
  const int quad = lane >> 4;
  const int kvh = w4;

  // hoist BOTH heads' Q loads before the barrier (overlap staging drain)
  const bf16_t* qrow0 = qkv + (size_t)(rowg0 + col) * 1536 + (half * 8 + w4) * 64;
  bf16x8 qfa0 = *(const bf16x8*)(qrow0 + quad * 8);
  bf16x8 qfa1 = *(const bf16x8*)(qrow0 + 32 + quad * 8);
  bf16x8 qfb0 = *(const bf16x8*)(qrow0 + 256 + quad * 8);      // head +4
  bf16x8 qfb1 = *(const bf16x8*)(qrow0 + 256 + 32 + quad * 8);

  __syncthreads();

  bf16x8 kf[2][2];
#pragma unroll
  for (int kt = 0; kt < 2; kt++)
#pragma unroll
    for (int kc2 = 0; kc2 < 2; kc2++)
      kf[kt][kc2] = *(const bf16x8*)(&Ks[kvh][kt * 16 + col][kc2 * 32 + quad * 8]);
  bf16x8 vf[4];
#pragma unroll
  for (int nt = 0; nt < 4; nt++) {
    int dim = nt * 16 + col;
    int kchunk = quad ^ ((dim >> 3) & 3);
    vf[nt] = *(const bf16x8*)(&VTs[kvh][dim][kchunk * 8]);
  }

  const bool t0dead = (i0loc == 0);

#pragma unroll
  for (int hp = 0; hp < 2; hp++) {
    const int h = half * 8 + w4 + hp * 4;
    const float slope = exp2f(-0.5f * (float)(h + 1));
    bf16x8 qf0 = hp ? qfb0 : qfa0;   // hp compile-time (unrolled)
    bf16x8 qf1 = hp ? qfb1 : qfa1;

    f32x4 s0 = {}, s1 = {};
    s0 = __builtin_amdgcn_mfma_f32_16x16x32_bf16(qf0, kf[0][0], s0, 0, 0, 0);
    s0 = __builtin_amdgcn_mfma_f32_16x16x32_bf16(qf1, kf[0][1], s0, 0, 0, 0);
    s1 = __builtin_amdgcn_mfma_f32_16x16x32_bf16(qf0, kf[1][0], s1, 0, 0, 0);
    s1 = __builtin_amdgcn_mfma_f32_16x16x32_bf16(qf1, kf[1][1], s1, 0, 0, 0);

    float sc0[4], sc1[4];
#pragma unroll
    for (int r = 0; r < 4; r++) {
      int rel0 = col - 16 - (quad * 4 + r);
      int rel1 = rel0 + 16;
      bool m0 = t0dead || (rel0 < -WINDOW);
      bool m1 = (rel1 > 0);
      sc0[r] = m0 ? -INFINITY : s0[r] * 0.125f + slope * (float)rel0;
      sc1[r] = m1 ? -INFINITY : s1[r] * 0.125f + slope * (float)rel1;
    }
    float mx[4], sum[4], p0[4], p1[4];
#pragma unroll
    for (int r = 0; r < 4; r++) mx[r] = fmaxf(sc0[r], sc1[r]);
#pragma unroll
    for (int off = 8; off >= 1; off >>= 1)
#pragma unroll
      for (int r = 0; r < 4; r++) mx[r] = fmaxf(mx[r], __shfl_xor(mx[r], off));
#pragma unroll
    for (int r = 0; r < 4; r++) {
      p0[r] = __expf(sc0[r] - mx[r]);
      p1[r] = __expf(sc1[r] - mx[r]);
      sum[r] = p0[r] + p1[r];
    }
#pragma unroll
    for (int off = 8; off >= 1; off >>= 1)
#pragma unroll
      for (int r = 0; r < 4; r++) sum[r] += __shfl_xor(sum[r], off);

#pragma unroll
    for (int r = 0; r < 4; r++) {
      Ps[w4][quad * 4 + r][col] = (bf16_t)p0[r];
      Ps[w4][quad * 4 + r][16 + col] = (bf16_t)p1[r];
    }
    // no __syncthreads: Ps slab is wave-private; DS ops in-order within a wave
    bf16x8 pf = *(const bf16x8*)(&Ps[w4][col][quad * 8]);

    f32x4 o[4] = {};
#pragma unroll
    for (int nt = 0; nt < 4; nt++)
      o[nt] = __builtin_amdgcn_mfma_f32_16x16x32_bf16(pf, vf[nt], o[nt], 0, 0, 0);

    float rs[4];
#pragma unroll
    for (int r = 0; r < 4; r++) rs[r] = __builtin_amdgcn_rcpf(sum[r]);
#pragma unroll
    for (int nt = 0; nt < 4; nt++)
#pragma unroll
      for (int r = 0; r < 4; r++)
        y[(size_t)(rowg0 + quad * 4 + r) * 1024 + h * 64 + nt * 16 + col] =
            (bf16_t)(o[nt][r] * rs[r]);
  }
}

extern "C" void kernel_launch(void* const* d_in, const int* in_sizes, int n_in,
                              void* d_out, int out_size, void* d_ws, size_t ws_size,
                              hipStream_t stream) {
  const float* x  = (const float*)d_in[0];
  const float* wq = (const float*)d_in[1];
  const float* wk = (const float*)d_in[2];
  const float* wv = (const float*)d_in[3];
  const float* wo = (const float*)d_in[4];
  const float* qw = (const float*)d_in[5];
  const float* kw = (const float*)d_in[6];
  float* out = (float*)d_out;

  const int M = 4096;  // B*L

  bf16_t* xb    = (bf16_t*)d_ws;
  bf16_t* wqkvb = xb + (size_t)M * DIM;        // [1536, 1024]
  bf16_t* wob   = wqkvb + (size_t)1536 * DIM;  // [1024, 1024]
  bf16_t* qkv   = wob + (size_t)DIM * DIM;     // [4096, 1536]
  bf16_t* yb    = qkv + (size_t)M * 1536;      // [4096, 1024]

  dim3 blk(256);
  f2bf_all<<<1703936 / 256, blk, 0, stream>>>(x, wq, wk, wv, wo, xb, wqkvb, wob);

  // QKV projection + fused RMSNorm: 768 blocks, XCD-swizzled (NBX=24, BYX=4)
  gemm_qkv_rms<<<768, blk, 0, stream>>>(xb, wqkvb, qkv, qw, kw, M, 1536, DIM);

  // attention: 512 blocks x 256 threads (qtile x head-half), 2+ blocks/CU
  attn_mfma<<<512, blk, 0, stream>>>(qkv, yb);

  // out projection: 512 blocks, XCD-swizzled (NBX=16, BYX=4)
  gemm_bf16<float, 16, 4><<<512, blk, 0, stream>>>(yb, wob, out, M, DIM, DIM);
}

// Round 8
// 124.579 us; speedup vs baseline: 4.6776x; 1.0016x over previous
//
#include <hip/hip_runtime.h>
#include <math.h>

#define DIM 1024
#define NH 16
#define NKV 4
#define HD 64
#define WINDOW 16
#define EPS 0.01f

typedef __bf16 bf16_t;
typedef bf16_t bf16x8 __attribute__((ext_vector_type(8)));
typedef bf16_t bf16x4 __attribute__((ext_vector_type(4)));
typedef float f32x4 __attribute__((ext_vector_type(4)));

// ============================================================================
// R19 = R14's verified pipeline (123.4us best) with exactly two deltas:
//  (a) f2bf widened to 32B/thread (R15-verified correctness; isolates R15's
//      regression attribution: epilogues vs f2bf width)
//  (b) attention epilogue: v_rcp + mul instead of 16 divides (verified R17/R18)
// Attention is R14's 1024-thread single-staging form (R18's dual-half remap
// staged each qtile's K/V twice -> +1.4us, reverted).
// Session ledger: harness fixed overhead ~88us (two 43.5us poison fills at
// HBM roofline inside timed window); kernel work ~36us; grid.sync fusion
// costs ~150us/barrier (rejected); 128x128 tile grid-starves at N<=1536
// (rejected); runtime-indexed acc -> scratch spill (rule #20, avoided).
// ============================================================================

// ---------------- fused fp32 -> bf16 conversion of all 5 tensors ----------------
__global__ __launch_bounds__(256) void f2bf_all(const float* __restrict__ x,
                                                const float* __restrict__ wq,
                                                const float* __restrict__ wk,
                                                const float* __restrict__ wv,
                                                const float* __restrict__ wo,
                                                bf16_t* __restrict__ xb,
                                                bf16_t* __restrict__ wqkvb,
                                                bf16_t* __restrict__ wob) {
  int i = blockIdx.x * blockDim.x + threadIdx.x;   // 8-elem chunk index
  const float* src;
  bf16_t* dst;
  int off;
  if (i < 524288) { src = x; dst = xb; off = i; }
  else if (i < 655360) { src = wq; dst = wqkvb; off = i - 524288; }
  else if (i < 688128) { src = wk; dst = wqkvb + (size_t)1024 * DIM; off = i - 655360; }
  else if (i < 720896) { src = wv; dst = wqkvb + (size_t)1280 * DIM; off = i - 688128; }
  else { src = wo; dst = wob; off = i - 720896; }
  float4 f0 = ((const float4*)src)[off * 2];
  float4 f1 = ((const float4*)src)[off * 2 + 1];
  bf16x8 o8 = {(bf16_t)f0.x, (bf16_t)f0.y, (bf16_t)f0.z, (bf16_t)f0.w,
               (bf16_t)f1.x, (bf16_t)f1.y, (bf16_t)f1.z, (bf16_t)f1.w};
  ((bf16x8*)dst)[off] = o8;
}

// ========== 128(M)x64(N), BK=64, double-buffered swizzled-staging GEMM ========
// split-K wave pairs: waves {0,1} rows 0-63, {2,3} rows 64-127; each wave
// computes a full 64x64 partial over its 32-wide k-half (h0=wid&1).
// 16 MFMA : 8 ds_read_b128 per k-step = 512B LDS/MFMA.
// GEMM_REDUCE: wave-uniform if(h0), compile-time acc indices ONLY (rule #20).
// LDS swizzle: row r, slot s holds global chunk kc=(s-r)&7; reader slot=(kc+r)&7.

#define GEMM_STAGE(buf, Ag, Bg)                                                 \
  {                                                                             \
    _Pragma("unroll")                                                           \
    for (int it = 0; it < 4; it++) {                                            \
      int c = it * 256 + t;                                                     \
      int r = c >> 3;                                                           \
      int kc = ((c & 7) - r) & 7;                                               \
      __builtin_amdgcn_global_load_lds(                                         \
          (const __attribute__((address_space(1))) void*)((Ag) + (size_t)r * K + kc * 8), \
          (__attribute__((address_space(3))) void*)(As[buf] + c * 8), 16, 0, 0); \
    }                                                                           \
    _Pragma("unroll")                                                           \
    for (int it = 0; it < 2; it++) {                                            \
      int c = it * 256 + t;                                                     \
      int r = c >> 3;                                                           \
      int kc = ((c & 7) - r) & 7;                                               \
      __builtin_amdgcn_global_load_lds(                                         \
          (const __attribute__((address_space(1))) void*)((Bg) + (size_t)r * K + kc * 8), \
          (__attribute__((address_space(3))) void*)(Bs[buf] + c * 8), 16, 0, 0); \
    }                                                                           \
  }

#define GEMM_DBUF_LOOP(Aptr, Bptr)                                              \
  {                                                                             \
    const bf16_t* Abase = Aptr + (size_t)row0 * K;                              \
    const bf16_t* Bbase = Bptr + (size_t)col0 * K;                              \
    GEMM_STAGE(0, Abase, Bbase)                                                 \
    const int nIter = K >> 6;                                                   \
    for (int ki = 0; ki < nIter; ki++) {                                        \
      __syncthreads();                                                          \
      if (ki + 1 < nIter)                                                       \
        GEMM_STAGE((ki + 1) & 1, Abase + (ki + 1) * 64, Bbase + (ki + 1) * 64)  \
      const bf16_t* Ab = As[ki & 1];                                            \
      const bf16_t* Bb = Bs[ki & 1];                                            \
      bf16x8 af[4], bfr[4];                                                     \
      _Pragma("unroll")                                                         \
      for (int mi = 0; mi < 4; mi++) af[mi] = *(const bf16x8*)(Ab + aoff[mi]);  \
      _Pragma("unroll")                                                         \
      for (int ni = 0; ni < 4; ni++) bfr[ni] = *(const bf16x8*)(Bb + boff[ni]); \
      _Pragma("unroll")                                                         \
      for (int mi = 0; mi < 4; mi++)                                            \
        _Pragma("unroll")                                                       \
        for (int ni = 0; ni < 4; ni++)                                          \
          acc[mi][ni] = __builtin_amdgcn_mfma_f32_16x16x32_bf16(af[mi], bfr[ni], \
                                                                acc[mi][ni], 0, 0, 0); \
    }                                                                           \
  }

#define GEMM_REDUCE()                                                           \
  {                                                                             \
    float* Xs = (float*)smem;                                                   \
    __syncthreads();                                                            \
    if (h0) {                                                                   \
      _Pragma("unroll")                                                         \
      for (int j = 0; j < 2; j++)                                               \
        _Pragma("unroll")                                                       \
        for (int ni = 0; ni < 4; ni++)                                          \
          *(f32x4*)(Xs + (size_t)(wid * 64 + ni * 16 + lcol) * 36 + j * 16 + lquad * 4) = \
              acc[j][ni];                                                       \
    } else {                                                                    \
      _Pragma("unroll")                                                         \
      for (int j = 0; j < 2; j++)                                               \
        _Pragma("unroll")                                                       \
        for (int ni = 0; ni < 4; ni++)                                          \
          *(f32x4*)(Xs + (size_t)(wid * 64 + ni * 16 + lcol) * 36 + j * 16 + lquad * 4) = \
              acc[2 + j][ni];                                                   \
    }                                                                           \
    __syncthreads();                                                            \
    if (h0) {                                                                   \
      _Pragma("unroll")                                                         \
      for (int j = 0; j < 2; j++)                                               \
        _Pragma("unroll")                                                       \
        for (int ni = 0; ni < 4; ni++) {                                        \
          f32x4 p = *(const f32x4*)(Xs + (size_t)((wid ^ 1) * 64 + ni * 16 + lcol) * 36 + \
                                    j * 16 + lquad * 4);                        \
          acc[j][ni] = acc[2 + j][ni] + p;                                      \
        }                                                                       \
    } else {                                                                    \
      _Pragma("unroll")                                                         \
      for (int j = 0; j < 2; j++)                                               \
        _Pragma("unroll")                                                       \
        for (int ni = 0; ni < 4; ni++) {                                        \
          f32x4 p = *(const f32x4*)(Xs + (size_t)((wid ^ 1) * 64 + ni * 16 + lcol) * 36 + \
                                    j * 16 + lquad * 4);                        \
          acc[j][ni] = acc[j][ni] + p;                                          \
        }                                                                       \
    }                                                                           \
  }

#define GEMM_PROLOGUE(NBX, BYX)                                                 \
  const int t = threadIdx.x;                                                    \
  const int lane = t & 63;                                                      \
  const int wid = t >> 6;                                                       \
  const int xcd = blockIdx.x & 7;                                               \
  const int jj = blockIdx.x >> 3;                                               \
  const int bx = jj % (NBX);                                                    \
  const int row0 = (xcd * (BYX) + jj / (NBX)) * 128;                            \
  const int col0 = bx * 64;                                                     \
  const int pr = (wid >> 1) * 64;                                               \
  const int h0 = wid & 1;                                                       \
  const int wm = wid * 32;                                                      \
  const int lquad = lane >> 4;                                                  \
  const int lcol = lane & 15;                                                   \
  int aoff[4], boff[4];                                                         \
  _Pragma("unroll")                                                             \
  for (int mi = 0; mi < 4; mi++) {                                              \
    int r = pr + mi * 16 + lcol;                                                \
    aoff[mi] = r * 64 + (((h0 * 4 + lquad) + r) & 7) * 8;                       \
  }                                                                             \
  _Pragma("unroll")                                                             \
  for (int ni = 0; ni < 4; ni++) {                                              \
    int r = ni * 16 + lcol;                                                     \
    boff[ni] = r * 64 + (((h0 * 4 + lquad) + r) & 7) * 8;                       \
  }                                                                             \
  f32x4 acc[4][4] = {};

// ---------------- QKV GEMM with fused per-head RMSNorm epilogue ----------------
__global__ __launch_bounds__(256, 3) void gemm_qkv_rms(const bf16_t* __restrict__ A,
                                                       const bf16_t* __restrict__ B,
                                                       bf16_t* __restrict__ C,
                                                       const float* __restrict__ qw,
                                                       const float* __restrict__ kw,
                                                       int M, int N, int K) {
  __shared__ __align__(16) char smem[49152];
  bf16_t (*As)[128 * 64] = (bf16_t(*)[128 * 64])smem;
  bf16_t (*Bs)[64 * 64] = (bf16_t(*)[64 * 64])(smem + 32768);
  GEMM_PROLOGUE(24, 4)
  GEMM_DBUF_LOOP(A, B)
  GEMM_REDUCE()

  const int hcol = bx;                   // 0..23
  const bool isv = (hcol >= 20);
  float wreg[4];
  if (!isv) {
    const float* wp = (hcol < 16) ? qw : kw;
#pragma unroll
    for (int ni = 0; ni < 4; ni++) wreg[ni] = wp[ni * 16 + lcol];
  }

#pragma unroll
  for (int mi = 0; mi < 2; mi++) {
#pragma unroll
    for (int r = 0; r < 4; r++) {
      float norm = 1.0f;
      if (!isv) {
        float ss = 0.0f;
#pragma unroll
        for (int ni = 0; ni < 4; ni++) ss += acc[mi][ni][r] * acc[mi][ni][r];
#pragma unroll
        for (int off = 8; off >= 1; off >>= 1) ss += __shfl_xor(ss, off);
        norm = rsqrtf(ss * (1.0f / 64.0f) + EPS);
      }
      size_t base = (size_t)(row0 + wm + mi * 16 + lquad * 4 + r) * N + col0 + lcol;
#pragma unroll
      for (int ni = 0; ni < 4; ni++) {
        float v = acc[mi][ni][r] * norm;
        if (!isv) v *= wreg[ni];
        C[base + ni * 16] = (bf16_t)v;
      }
    }
  }
}

// ---------------- bf16 MFMA GEMM (128x64, split-K waves, XCD-swizzled) --------
template <typename CT, int NBX, int BYX>
__global__ __launch_bounds__(256, 3) void gemm_bf16(const bf16_t* __restrict__ A,
                                                    const bf16_t* __restrict__ B,
                                                    CT* __restrict__ C,
                                                    int M, int N, int K) {
  __shared__ __align__(16) char smem[49152];
  bf16_t (*As)[128 * 64] = (bf16_t(*)[128 * 64])smem;
  bf16_t (*Bs)[64 * 64] = (bf16_t(*)[64 * 64])(smem + 32768);
  GEMM_PROLOGUE(NBX, BYX)
  GEMM_DBUF_LOOP(A, B)
  GEMM_REDUCE()

#pragma unroll
  for (int mi = 0; mi < 2; mi++)
#pragma unroll
    for (int ni = 0; ni < 4; ni++) {
      size_t base = (size_t)(row0 + wm + mi * 16 + lquad * 4) * N + col0 + ni * 16 + lcol;
#pragma unroll
      for (int r = 0; r < 4; r++)
        C[base + (size_t)r * N] = (CT)acc[mi][ni][r];
    }
}

// ---------------- MFMA banded ALiBi attention (shared K/V staging) -----------
#define LKP 72  // K row stride (keys x dims)
#define LVP 40  // VT / P row stride

__global__ __launch_bounds__(1024) void attn_mfma(const bf16_t* __restrict__ qkv,
                                                  bf16_t* __restrict__ y) {
  __shared__ bf16_t Ks[4][32][LKP];    // [kvh][key][dim]
  __shared__ bf16_t VTs[4][64][LVP];   // [kvh][dim][swizzled key]
  __shared__ bf16_t Ps[16][16][LVP];   // [wave][qrow][key]

  const int t = threadIdx.x;
  const int lane = t & 63;
  const int w = t >> 6;                // 0..15 = head
  const int b = blockIdx.x >> 7;
  const int i0loc = (blockIdx.x & 127) << 4;
  const int rowbase = b << 11;
  const int rowg0 = rowbase + i0loc;

  // ---- stage K and V once: thread t handles chunk t (kvh, key, 16B dim-chunk)
  {
    int kvh = t >> 8;
    int key = (t >> 3) & 31;
    int dc = t & 7;
    int jloc = i0loc - 16 + key;
    int rg = rowbase + (jloc < 0 ? 0 : jloc);
    const bf16_t* src = qkv + (size_t)rg * 1536 + 1024 + kvh * 64 + dc * 8;
    bf16x8 kval = *(const bf16x8*)src;
    *(bf16x8*)(&Ks[kvh][key][dc * 8]) = kval;
    bf16x8 vval = *(const bf16x8*)(src + 256);   // V is 256 elems after K
    int kslot = ((key >> 3) ^ (dc & 3)) * 8 + (key & 7);
#pragma unroll
    for (int e = 0; e < 8; e++) VTs[kvh][dc * 8 + e][kslot] = vval[e];
  }

  const int col = lane & 15;
  const int quad = lane >> 4;
  const int h = w;
  const int kvh = w & 3;
  const float slope = exp2f(-0.5f * (float)(h + 1));

  // Q loads issued BEFORE the barrier: their HBM/L2 latency overlaps the
  // staging drain (1 block/CU kernel -> no other waves to hide it).
  const bf16_t* qrow = qkv + (size_t)(rowg0 + col) * 1536 + h * 64;
  bf16x8 qf0 = *(const bf16x8*)(qrow + quad * 8);
  bf16x8 qf1 = *(const bf16x8*)(qrow + 32 + quad * 8);

  __syncthreads();

  bf16x8 kf[2][2];
#pragma unroll
  for (int kt = 0; kt < 2; kt++)
#pragma unroll
    for (int kc = 0; kc < 2; kc++)
      kf[kt][kc] = *(const bf16x8*)(&Ks[kvh][kt * 16 + col][kc * 32 + quad * 8]);
  bf16x8 vf[4];
#pragma unroll
  for (int nt = 0; nt < 4; nt++) {
    int dim = nt * 16 + col;
    int kchunk = quad ^ ((dim >> 3) & 3);
    vf[nt] = *(const bf16x8*)(&VTs[kvh][dim][kchunk * 8]);
  }

  f32x4 s0 = {}, s1 = {};
  s0 = __builtin_amdgcn_mfma_f32_16x16x32_bf16(qf0, kf[0][0], s0, 0, 0, 0);
  s0 = __builtin_amdgcn_mfma_f32_16x16x32_bf16(qf1, kf[0][1], s0, 0, 0, 0);
  s1 = __builtin_amdgcn_mfma_f32_16x16x32_bf16(qf0, kf[1][0], s1, 0, 0, 0);
  s1 = __builtin_amdgcn_mfma_f32_16x16x32_bf16(qf1, kf[1][1], s1, 0, 0, 0);

  const bool t0dead = (i0loc == 0);
  float sc0[4], sc1[4];
#pragma unroll
  for (int r = 0; r < 4; r++) {
    int rel0 = col - 16 - (quad * 4 + r);
    int rel1 = rel0 + 16;
    bool m0 = t0dead || (rel0 < -WINDOW);
    bool m1 = (rel1 > 0);
    sc0[r] = m0 ? -INFINITY : s0[r] * 0.125f + slope * (float)rel0;
    sc1[r] = m1 ? -INFINITY : s1[r] * 0.125f + slope * (float)rel1;
  }
  float mx[4], sum[4], p0[4], p1[4];
#pragma unroll
  for (int r = 0; r < 4; r++) mx[r] = fmaxf(sc0[r], sc1[r]);
#pragma unroll
  for (int off = 8; off >= 1; off >>= 1)
#pragma unroll
    for (int r = 0; r < 4; r++) mx[r] = fmaxf(mx[r], __shfl_xor(mx[r], off));
#pragma unroll
  for (int r = 0; r < 4; r++) {
    p0[r] = __expf(sc0[r] - mx[r]);
    p1[r] = __expf(sc1[r] - mx[r]);
    sum[r] = p0[r] + p1[r];
  }
#pragma unroll
  for (int off = 8; off >= 1; off >>= 1)
#pragma unroll
    for (int r = 0; r < 4; r++) sum[r] += __shfl_xor(sum[r], off);

#pragma unroll
  for (int r = 0; r < 4; r++) {
    Ps[w][quad * 4 + r][col] = (bf16_t)p0[r];
    Ps[w][quad * 4 + r][16 + col] = (bf16_t)p1[r];
  }
  // no __syncthreads: Ps[w] is wave-private; DS ops in-order within a wave
  bf16x8 pf = *(const bf16x8*)(&Ps[w][col][quad * 8]);

  f32x4 o[4] = {};
#pragma unroll
  for (int nt = 0; nt < 4; nt++)
    o[nt] = __builtin_amdgcn_mfma_f32_16x16x32_bf16(pf, vf[nt], o[nt], 0, 0, 0);

  float rs[4];
#pragma unroll
  for (int r = 0; r < 4; r++) rs[r] = __builtin_amdgcn_rcpf(sum[r]);
#pragma unroll
  for (int nt = 0; nt < 4; nt++)
#pragma unroll
    for (int r = 0; r < 4; r++)
      y[(size_t)(rowg0 + quad * 4 + r) * 1024 + h * 64 + nt * 16 + col] =
          (bf16_t)(o[nt][r] * rs[r]);
}

extern "C" void kernel_launch(void* const* d_in, const int* in_sizes, int n_in,
                              void* d_out, int out_size, void* d_ws, size_t ws_size,
                              hipStream_t stream) {
  const float* x  = (const float*)d_in[0];
  const float* wq = (const float*)d_in[1];
  const float* wk = (const float*)d_in[2];
  const float* wv = (const float*)d_in[3];
  const float* wo = (const float*)d_in[4];
  const float* qw = (const float*)d_in[5];
  const float* kw = (const float*)d_in[6];
  float* out = (float*)d_out;

  const int M = 4096;  // B*L

  bf16_t* xb    = (bf16_t*)d_ws;
  bf16_t* wqkvb = xb + (size_t)M * DIM;        // [1536, 1024]
  bf16_t* wob   = wqkvb + (size_t)1536 * DIM;  // [1024, 1024]
  bf16_t* qkv   = wob + (size_t)DIM * DIM;     // [4096, 1536]
  bf16_t* yb    = qkv + (size_t)M * 1536;      // [4096, 1024]

  dim3 blk(256);
  f2bf_all<<<3328, blk, 0, stream>>>(x, wq, wk, wv, wo, xb, wqkvb, wob);

  // QKV projection + fused RMSNorm: 768 blocks, XCD-swizzled (NBX=24, BYX=4)
  gemm_qkv_rms<<<768, blk, 0, stream>>>(xb, wqkvb, qkv, qw, kw, M, 1536, DIM);

  // attention: 256 blocks x 1024 threads, shared K/V staging (once per qtile)
  attn_mfma<<<256, dim3(1024), 0, stream>>>(qkv, yb);

  // out projection: 512 blocks, XCD-swizzled (NBX=16, BYX=4)
  gemm_bf16<float, 16, 4><<<512, blk, 0, stream>>>(yb, wob, out, M, DIM, DIM);
}

// Round 9
// 124.122 us; speedup vs baseline: 4.6948x; 1.0037x over previous
//
#include <hip/hip_runtime.h>
#include <math.h>

#define DIM 1024
#define NH 16
#define NKV 4
#define HD 64
#define WINDOW 16
#define EPS 0.01f

typedef __bf16 bf16_t;
typedef bf16_t bf16x8 __attribute__((ext_vector_type(8)));
typedef bf16_t bf16x4 __attribute__((ext_vector_type(4)));
typedef float f32x4 __attribute__((ext_vector_type(4)));

// ============================================================================
// R20 = R14 byte-for-byte: the best-measured configuration (123.4us).
// Session ledger (why this is terminal):
//  - Fixed harness overhead ~88us: two ~43.5us poison fills inside the timed
//    window, running at 6.2 TB/s = the achievable HBM ceiling. Not controllable.
//  - Kernel work ~35us: f2bf ~6.5us (41MB @ HBM roofline), attn ~5us,
//    GEMMs ~24us for 21.5 GFLOP = ~900 TF effective = the measured structural
//    ceiling of the 128-tile/2-barrier HIP GEMM family.
//  - Tested and rejected: 128x128 tile (grid-starves at N<=1536, 135us),
//    B-direct-from-global (compiler sinks loads), LDS-transpose epilogues
//    (+4.7us), dual-half attention remap (+1.4us, double K/V staging),
//    cooperative grid.sync fusion (~150us/barrier, 582us), wide-f2bf + rcp
//    epilogue (noise). Kept: split-K wave pairs (-3.4us, R14).
//  - Rule #20 honored everywhere: no runtime-indexed ext_vector arrays.
// ============================================================================

// ---------------- fused fp32 -> bf16 conversion of all 5 tensors ----------------
__global__ __launch_bounds__(256) void f2bf_all(const float* __restrict__ x,
                                                const float* __restrict__ wq,
                                                const float* __restrict__ wk,
                                                const float* __restrict__ wv,
                                                const float* __restrict__ wo,
                                                bf16_t* __restrict__ xb,
                                                bf16_t* __restrict__ wqkvb,
                                                bf16_t* __restrict__ wob) {
  int i = blockIdx.x * blockDim.x + threadIdx.x;
  const float* src;
  bf16_t* dst;
  int off;
  if (i < 1048576) { src = x; dst = xb; off = i; }
  else if (i < 1310720) { src = wq; dst = wqkvb; off = i - 1048576; }
  else if (i < 1376256) { src = wk; dst = wqkvb + (size_t)1024 * DIM; off = i - 1310720; }
  else if (i < 1441792) { src = wv; dst = wqkvb + (size_t)1280 * DIM; off = i - 1376256; }
  else { src = wo; dst = wob; off = i - 1441792; }
  float4 f = ((const float4*)src)[off];
  bf16x4 o = {(bf16_t)f.x, (bf16_t)f.y, (bf16_t)f.z, (bf16_t)f.w};
  ((bf16x4*)dst)[off] = o;
}

// ========== 128(M)x64(N), BK=64, double-buffered swizzled-staging GEMM ========
// split-K wave pairs: waves {0,1} rows 0-63, {2,3} rows 64-127; each wave
// computes a full 64x64 partial over its 32-wide k-half (h0=wid&1).
// 16 MFMA : 8 ds_read_b128 per k-step = 512B LDS/MFMA.
// GEMM_REDUCE: wave-uniform if(h0), compile-time acc indices ONLY (rule #20).
// LDS swizzle: row r, slot s holds global chunk kc=(s-r)&7; reader slot=(kc+r)&7.

#define GEMM_STAGE(buf, Ag, Bg)                                                 \
  {                                                                             \
    _Pragma("unroll")                                                           \
    for (int it = 0; it < 4; it++) {                                            \
      int c = it * 256 + t;                                                     \
      int r = c >> 3;                                                           \
      int kc = ((c & 7) - r) & 7;                                               \
      __builtin_amdgcn_global_load_lds(                                         \
          (const __attribute__((address_space(1))) void*)((Ag) + (size_t)r * K + kc * 8), \
          (__attribute__((address_space(3))) void*)(As[buf] + c * 8), 16, 0, 0); \
    }                                                                           \
    _Pragma("unroll")                                                           \
    for (int it = 0; it < 2; it++) {                                            \
      int c = it * 256 + t;                                                     \
      int r = c >> 3;                                                           \
      int kc = ((c & 7) - r) & 7;                                               \
      __builtin_amdgcn_global_load_lds(                                         \
          (const __attribute__((address_space(1))) void*)((Bg) + (size_t)r * K + kc * 8), \
          (__attribute__((address_space(3))) void*)(Bs[buf] + c * 8), 16, 0, 0); \
    }                                                                           \
  }

#define GEMM_DBUF_LOOP(Aptr, Bptr)                                              \
  {                                                                             \
    const bf16_t* Abase = Aptr + (size_t)row0 * K;                              \
    const bf16_t* Bbase = Bptr + (size_t)col0 * K;                              \
    GEMM_STAGE(0, Abase, Bbase)                                                 \
    const int nIter = K >> 6;                                                   \
    for (int ki = 0; ki < nIter; ki++) {                                        \
      __syncthreads();                                                          \
      if (ki + 1 < nIter)                                                       \
        GEMM_STAGE((ki + 1) & 1, Abase + (ki + 1) * 64, Bbase + (ki + 1) * 64)  \
      const bf16_t* Ab = As[ki & 1];                                            \
      const bf16_t* Bb = Bs[ki & 1];                                            \
      bf16x8 af[4], bfr[4];                                                     \
      _Pragma("unroll")                                                         \
      for (int mi = 0; mi < 4; mi++) af[mi] = *(const bf16x8*)(Ab + aoff[mi]);  \
      _Pragma("unroll")                                                         \
      for (int ni = 0; ni < 4; ni++) bfr[ni] = *(const bf16x8*)(Bb + boff[ni]); \
      _Pragma("unroll")                                                         \
      for (int mi = 0; mi < 4; mi++)                                            \
        _Pragma("unroll")                                                       \
        for (int ni = 0; ni < 4; ni++)                                          \
          acc[mi][ni] = __builtin_amdgcn_mfma_f32_16x16x32_bf16(af[mi], bfr[ni], \
                                                                acc[mi][ni], 0, 0, 0); \
    }                                                                           \
  }

#define GEMM_REDUCE()                                                           \
  {                                                                             \
    float* Xs = (float*)smem;                                                   \
    __syncthreads();                                                            \
    if (h0) {                                                                   \
      _Pragma("unroll")                                                         \
      for (int j = 0; j < 2; j++)                                               \
        _Pragma("unroll")                                                       \
        for (int ni = 0; ni < 4; ni++)                                          \
          *(f32x4*)(Xs + (size_t)(wid * 64 + ni * 16 + lcol) * 36 + j * 16 + lquad * 4) = \
              acc[j][ni];                                                       \
    } else {                                                                    \
      _Pragma("unroll")                                                         \
      for (int j = 0; j < 2; j++)                                               \
        _Pragma("unroll")                                                       \
        for (int ni = 0; ni < 4; ni++)                                          \
          *(f32x4*)(Xs + (size_t)(wid * 64 + ni * 16 + lcol) * 36 + j * 16 + lquad * 4) = \
              acc[2 + j][ni];                                                   \
    }                                                                           \
    __syncthreads();                                                            \
    if (h0) {                                                                   \
      _Pragma("unroll")                                                         \
      for (int j = 0; j < 2; j++)                                               \
        _Pragma("unroll")                                                       \
        for (int ni = 0; ni < 4; ni++) {                                        \
          f32x4 p = *(const f32x4*)(Xs + (size_t)((wid ^ 1) * 64 + ni * 16 + lcol) * 36 + \
                                    j * 16 + lquad * 4);                        \
          acc[j][ni] = acc[2 + j][ni] + p;                                      \
        }                                                                       \
    } else {                                                                    \
      _Pragma("unroll")                                                         \
      for (int j = 0; j < 2; j++)                                               \
        _Pragma("unroll")                                                       \
        for (int ni = 0; ni < 4; ni++) {                                        \
          f32x4 p = *(const f32x4*)(Xs + (size_t)((wid ^ 1) * 64 + ni * 16 + lcol) * 36 + \
                                    j * 16 + lquad * 4);                        \
          acc[j][ni] = acc[j][ni] + p;                                          \
        }                                                                       \
    }                                                                           \
  }

#define GEMM_PROLOGUE(NBX, BYX)                                                 \
  const int t = threadIdx.x;                                                    \
  const int lane = t & 63;                                                      \
  const int wid = t >> 6;                                                       \
  const int xcd = blockIdx.x & 7;                                               \
  const int jj = blockIdx.x >> 3;                                               \
  const int bx = jj % (NBX);                                                    \
  const int row0 = (xcd * (BYX) + jj / (NBX)) * 128;                            \
  const int col0 = bx * 64;                                                     \
  const int pr = (wid >> 1) * 64;                                               \
  const int h0 = wid & 1;                                                       \
  const int wm = wid * 32;                                                      \
  const int lquad = lane >> 4;                                                  \
  const int lcol = lane & 15;                                                   \
  int aoff[4], boff[4];                                                         \
  _Pragma("unroll")                                                             \
  for (int mi = 0; mi < 4; mi++) {                                              \
    int r = pr + mi * 16 + lcol;                                                \
    aoff[mi] = r * 64 + (((h0 * 4 + lquad) + r) & 7) * 8;                       \
  }                                                                             \
  _Pragma("unroll")                                                             \
  for (int ni = 0; ni < 4; ni++) {                                              \
    int r = ni * 16 + lcol;                                                     \
    boff[ni] = r * 64 + (((h0 * 4 + lquad) + r) & 7) * 8;                       \
  }                                                                             \
  f32x4 acc[4][4] = {};

// ---------------- QKV GEMM with fused per-head RMSNorm epilogue ----------------
__global__ __launch_bounds__(256, 3) void gemm_qkv_rms(const bf16_t* __restrict__ A,
                                                       const bf16_t* __restrict__ B,
                                                       bf16_t* __restrict__ C,
                                                       const float* __restrict__ qw,
                                                       const float* __restrict__ kw,
                                                       int M, int N, int K) {
  __shared__ __align__(16) char smem[49152];
  bf16_t (*As)[128 * 64] = (bf16_t(*)[128 * 64])smem;
  bf16_t (*Bs)[64 * 64] = (bf16_t(*)[64 * 64])(smem + 32768);
  GEMM_PROLOGUE(24, 4)
  GEMM_DBUF_LOOP(A, B)
  GEMM_REDUCE()

  const int hcol = bx;                   // 0..23
  const bool isv = (hcol >= 20);
  float wreg[4];
  if (!isv) {
    const float* wp = (hcol < 16) ? qw : kw;
#pragma unroll
    for (int ni = 0; ni < 4; ni++) wreg[ni] = wp[ni * 16 + lcol];
  }

#pragma unroll
  for (int mi = 0; mi < 2; mi++) {
#pragma unroll
    for (int r = 0; r < 4; r++) {
      float norm = 1.0f;
      if (!isv) {
        float ss = 0.0f;
#pragma unroll
        for (int ni = 0; ni < 4; ni++) ss += acc[mi][ni][r] * acc[mi][ni][r];
#pragma unroll
        for (int off = 8; off >= 1; off >>= 1) ss += __shfl_xor(ss, off);
        norm = rsqrtf(ss * (1.0f / 64.0f) + EPS);
      }
      size_t base = (size_t)(row0 + wm + mi * 16 + lquad * 4 + r) * N + col0 + lcol;
#pragma unroll
      for (int ni = 0; ni < 4; ni++) {
        float v = acc[mi][ni][r] * norm;
        if (!isv) v *= wreg[ni];
        C[base + ni * 16] = (bf16_t)v;
      }
    }
  }
}

// ---------------- bf16 MFMA GEMM (128x64, split-K waves, XCD-swizzled) --------
template <typename CT, int NBX, int BYX>
__global__ __launch_bounds__(256, 3) void gemm_bf16(const bf16_t* __restrict__ A,
                                                    const bf16_t* __restrict__ B,
                                                    CT* __restrict__ C,
                                                    int M, int N, int K) {
  __shared__ __align__(16) char smem[49152];
  bf16_t (*As)[128 * 64] = (bf16_t(*)[128 * 64])smem;
  bf16_t (*Bs)[64 * 64] = (bf16_t(*)[64 * 64])(smem + 32768);
  GEMM_PROLOGUE(NBX, BYX)
  GEMM_DBUF_LOOP(A, B)
  GEMM_REDUCE()

#pragma unroll
  for (int mi = 0; mi < 2; mi++)
#pragma unroll
    for (int ni = 0; ni < 4; ni++) {
      size_t base = (size_t)(row0 + wm + mi * 16 + lquad * 4) * N + col0 + ni * 16 + lcol;
#pragma unroll
      for (int r = 0; r < 4; r++)
        C[base + (size_t)r * N] = (CT)acc[mi][ni][r];
    }
}

// ---------------- MFMA banded ALiBi attention (shared K/V staging) -----------
#define LKP 72  // K row stride (keys x dims)
#define LVP 40  // VT / P row stride

__global__ __launch_bounds__(1024) void attn_mfma(const bf16_t* __restrict__ qkv,
                                                  bf16_t* __restrict__ y) {
  __shared__ bf16_t Ks[4][32][LKP];    // [kvh][key][dim]
  __shared__ bf16_t VTs[4][64][LVP];   // [kvh][dim][swizzled key]
  __shared__ bf16_t Ps[16][16][LVP];   // [wave][qrow][key]

  const int t = threadIdx.x;
  const int lane = t & 63;
  const int w = t >> 6;                // 0..15 = head
  const int b = blockIdx.x >> 7;
  const int i0loc = (blockIdx.x & 127) << 4;
  const int rowbase = b << 11;
  const int rowg0 = rowbase + i0loc;

  // ---- stage K and V once: thread t handles chunk t (kvh, key, 16B dim-chunk)
  {
    int kvh = t >> 8;
    int key = (t >> 3) & 31;
    int dc = t & 7;
    int jloc = i0loc - 16 + key;
    int rg = rowbase + (jloc < 0 ? 0 : jloc);
    const bf16_t* src = qkv + (size_t)rg * 1536 + 1024 + kvh * 64 + dc * 8;
    bf16x8 kval = *(const bf16x8*)src;
    *(bf16x8*)(&Ks[kvh][key][dc * 8]) = kval;
    bf16x8 vval = *(const bf16x8*)(src + 256);   // V is 256 elems after K
    int kslot = ((key >> 3) ^ (dc & 3)) * 8 + (key & 7);
#pragma unroll
    for (int e = 0; e < 8; e++) VTs[kvh][dc * 8 + e][kslot] = vval[e];
  }

  const int col = lane & 15;
  const int quad = lane >> 4;
  const int h = w;
  const int kvh = w & 3;
  const float slope = exp2f(-0.5f * (float)(h + 1));

  // Q loads issued BEFORE the barrier: their HBM/L2 latency overlaps the
  // staging drain (1 block/CU kernel -> no other waves to hide it).
  const bf16_t* qrow = qkv + (size_t)(rowg0 + col) * 1536 + h * 64;
  bf16x8 qf0 = *(const bf16x8*)(qrow + quad * 8);
  bf16x8 qf1 = *(const bf16x8*)(qrow + 32 + quad * 8);

  __syncthreads();

  bf16x8 kf[2][2];
#pragma unroll
  for (int kt = 0; kt < 2; kt++)
#pragma unroll
    for (int kc = 0; kc < 2; kc++)
      kf[kt][kc] = *(const bf16x8*)(&Ks[kvh][kt * 16 + col][kc * 32 + quad * 8]);
  bf16x8 vf[4];
#pragma unroll
  for (int nt = 0; nt < 4; nt++) {
    int dim = nt * 16 + col;
    int kchunk = quad ^ ((dim >> 3) & 3);
    vf[nt] = *(const bf16x8*)(&VTs[kvh][dim][kchunk * 8]);
  }

  f32x4 s0 = {}, s1 = {};
  s0 = __builtin_amdgcn_mfma_f32_16x16x32_bf16(qf0, kf[0][0], s0, 0, 0, 0);
  s0 = __builtin_amdgcn_mfma_f32_16x16x32_bf16(qf1, kf[0][1], s0, 0, 0, 0);
  s1 = __builtin_amdgcn_mfma_f32_16x16x32_bf16(qf0, kf[1][0], s1, 0, 0, 0);
  s1 = __builtin_amdgcn_mfma_f32_16x16x32_bf16(qf1, kf[1][1], s1, 0, 0, 0);

  const bool t0dead = (i0loc == 0);
  float sc0[4], sc1[4];
#pragma unroll
  for (int r = 0; r < 4; r++) {
    int rel0 = col - 16 - (quad * 4 + r);
    int rel1 = rel0 + 16;
    bool m0 = t0dead || (rel0 < -WINDOW);
    bool m1 = (rel1 > 0);
    sc0[r] = m0 ? -INFINITY : s0[r] * 0.125f + slope * (float)rel0;
    sc1[r] = m1 ? -INFINITY : s1[r] * 0.125f + slope * (float)rel1;
  }
  float mx[4], sum[4], p0[4], p1[4];
#pragma unroll
  for (int r = 0; r < 4; r++) mx[r] = fmaxf(sc0[r], sc1[r]);
#pragma unroll
  for (int off = 8; off >= 1; off >>= 1)
#pragma unroll
    for (int r = 0; r < 4; r++) mx[r] = fmaxf(mx[r], __shfl_xor(mx[r], off));
#pragma unroll
  for (int r = 0; r < 4; r++) {
    p0[r] = __expf(sc0[r] - mx[r]);
    p1[r] = __expf(sc1[r] - mx[r]);
    sum[r] = p0[r] + p1[r];
  }
#pragma unroll
  for (int off = 8; off >= 1; off >>= 1)
#pragma unroll
    for (int r = 0; r < 4; r++) sum[r] += __shfl_xor(sum[r], off);

#pragma unroll
  for (int r = 0; r < 4; r++) {
    Ps[w][quad * 4 + r][col] = (bf16_t)p0[r];
    Ps[w][quad * 4 + r][16 + col] = (bf16_t)p1[r];
  }
  // no __syncthreads: Ps[w] is wave-private; DS ops in-order within a wave
  bf16x8 pf = *(const bf16x8*)(&Ps[w][col][quad * 8]);

  f32x4 o[4] = {};
#pragma unroll
  for (int nt = 0; nt < 4; nt++)
    o[nt] = __builtin_amdgcn_mfma_f32_16x16x32_bf16(pf, vf[nt], o[nt], 0, 0, 0);

#pragma unroll
  for (int nt = 0; nt < 4; nt++)
#pragma unroll
    for (int r = 0; r < 4; r++)
      y[(size_t)(rowg0 + quad * 4 + r) * 1024 + h * 64 + nt * 16 + col] =
          (bf16_t)(o[nt][r] / sum[r]);
}

extern "C" void kernel_launch(void* const* d_in, const int* in_sizes, int n_in,
                              void* d_out, int out_size, void* d_ws, size_t ws_size,
                              hipStream_t stream) {
  const float* x  = (const float*)d_in[0];
  const float* wq = (const float*)d_in[1];
  const float* wk = (const float*)d_in[2];
  const float* wv = (const float*)d_in[3];
  const float* wo = (const float*)d_in[4];
  const float* qw = (const float*)d_in[5];
  const float* kw = (const float*)d_in[6];
  float* out = (float*)d_out;

  const int M = 4096;  // B*L

  bf16_t* xb    = (bf16_t*)d_ws;
  bf16_t* wqkvb = xb + (size_t)M * DIM;        // [1536, 1024]
  bf16_t* wob   = wqkvb + (size_t)1536 * DIM;  // [1024, 1024]
  bf16_t* qkv   = wob + (size_t)DIM * DIM;     // [4096, 1536]
  bf16_t* yb    = qkv + (size_t)M * 1536;      // [4096, 1024]

  dim3 blk(256);
  f2bf_all<<<1703936 / 256, blk, 0, stream>>>(x, wq, wk, wv, wo, xb, wqkvb, wob);

  // QKV projection + fused RMSNorm: 768 blocks, XCD-swizzled (NBX=24, BYX=4)
  gemm_qkv_rms<<<768, blk, 0, stream>>>(xb, wqkvb, qkv, qw, kw, M, 1536, DIM);

  // attention: 256 blocks x 1024 threads, shared K/V staging (once per qtile)
  attn_mfma<<<256, dim3(1024), 0, stream>>>(qkv, yb);

  // out projection: 512 blocks, XCD-swizzled (NBX=16, BYX=4)
  gemm_bf16<float, 16, 4><<<512, blk, 0, stream>>>(yb, wob, out, M, DIM, DIM);
}